// Round 7
// baseline (2483.391 us; speedup 1.0000x reference)
//
#include <hip/hip_runtime.h>
#include <math.h>

// Problem constants (fixed by the reference)
#define BB     2
#define LL     1024
#define CC     4
#define EE     256
#define HH     8
#define DD     32
#define NLAYER 2
#define W1N    257          // WIN+1
#define INPAIR 1028         // C*(WIN+1)
#define KP1    1056         // INPAIR padded to 32
#define HIDN   512
#define NCN    10
#define SCALEF 0.17677669529663687f   // 32^-0.5
#define GRID   512          // persistent blocks: 2/CU x 256 CU, co-resident by construction

typedef short bf16x8 __attribute__((ext_vector_type(8)));
typedef float f32x4  __attribute__((ext_vector_type(4)));
typedef unsigned short u16x4 __attribute__((ext_vector_type(4)));
typedef unsigned short u16x8 __attribute__((ext_vector_type(8)));

__device__ __forceinline__ float gelu_f(float x) {
    return 0.5f * x * (1.0f + erff(x * 0.7071067811865475f));
}
__device__ __forceinline__ unsigned short f2bf(float f) {
    unsigned u = __float_as_uint(f);
    u += 0x7fffu + ((u >> 16) & 1u);      // RNE
    return (unsigned short)(u >> 16);
}

struct PrepDesc {
    const float* src[14];
    int K[14];
    int N[14];
    unsigned long long dst[14];
};

// weight-pool sub-offsets (ushort units)
#define OFF_PW1  0            // 1056*256
#define OFF_PW2  270336
#define OFF_QKVO 335872       // 8 * 65536
#define OFF_FW1  860160       // 2 * 131072
#define OFF_FW2  1122304      // 2 * 131072

struct Params {
    // inputs
    const int* tokens; const float* xp; const float* bias; const float* mask;
    const float* temb; const float* pe;
    const float* pb1; const float* pb2;
    const float* ln1g; const float* ln1b;
    const float* bq; const float* bk; const float* bv; const float* bo;
    const float* gate; const float* ln2g; const float* ln2b;
    const float* fb1; const float* fb2;
    const float* hlng; const float* hlnb;
    const float* hw1; const float* hb1; const float* hw2; const float* hb2;
    PrepDesc pd;
    // workspace
    float* x; float* Opart; float* statsM; float* statsL; float* part; float* pmask;
    unsigned short* qb16; unsigned short* kswz; unsigned short* vswz;
    unsigned short* xn; unsigned short* aob; unsigned short* ffh;
    unsigned short* ph; unsigned short* flat; unsigned short* wt;
    unsigned* cnt;
    float* outp;
};

// ---------------------------------------------------------------------------
// device-wide barrier: one monotone counter per barrier index (memset to 0
// each launch). All GRID blocks call every barrier in the same order.
// ---------------------------------------------------------------------------
__device__ __forceinline__ void gbar(unsigned* c) {
    __syncthreads();
    __threadfence();     // release: make this block's writes device-visible
    if (threadIdx.x == 0) {
        __hip_atomic_fetch_add(c, 1u, __ATOMIC_RELEASE, __HIP_MEMORY_SCOPE_AGENT);
        while (__hip_atomic_load(c, __ATOMIC_ACQUIRE, __HIP_MEMORY_SCOPE_AGENT) < (unsigned)GRID)
            __builtin_amdgcn_s_sleep(8);
    }
    __syncthreads();
    __threadfence();     // acquire: invalidate stale cached lines for all waves
}

// ---------------------------------------------------------------------------
// phase bodies (ports of the validated R5 kernels)
// ---------------------------------------------------------------------------
__device__ __forceinline__ void prep_item(const Params& P, int it) {
    const int mi = it / 132, k8 = it - mi * 132;
    const int K = P.pd.K[mi], N = P.pd.N[mi];
    const int Kp = (K + 31) & ~31;
    if (k8 * 8 >= Kp) return;
    const float* src = P.pd.src[mi];
    unsigned short* dst = P.wt + P.pd.dst[mi];
    for (int n = threadIdx.x; n < N; n += 256) {
        u16x8 o;
        #pragma unroll
        for (int j = 0; j < 8; ++j) {
            int k = k8 * 8 + j;
            float v = (k < K) ? src[(size_t)k * N + n] : 0.f;
            o[j] = f2bf(v);
        }
        *(u16x8*)(dst + ((size_t)k8 * N + n) * 8) = o;
    }
}

__device__ __forceinline__ void gather_item(const Params& P, int row) {
    const int b = row >> 10, l = row & 1023;
    const float* base = P.xp + (size_t)b * CC * LL * LL + (size_t)l * LL;
    for (int kp = threadIdx.x; kp < KP1; kp += 256) {
        float v = 0.f;
        if (kp < INPAIR) {
            int c = kp / W1N;
            int w = kp - c * W1N;
            int col = l + w - 128;
            if (col >= 0 && col < LL) v = base[(size_t)c * LL * LL + col];
        }
        P.flat[(size_t)row * KP1 + kp] = f2bf(v);
    }
}

__device__ __forceinline__ void ln_item(
    const float* __restrict__ x, const float* __restrict__ g,
    const float* __restrict__ bt, unsigned short* __restrict__ out, int it)
{
    const int row = it * 4 + (threadIdx.x >> 6);
    const int lane = threadIdx.x & 63;
    float4 v = *(const float4*)(x + (size_t)row * EE + lane * 4);
    float s = v.x + v.y + v.z + v.w;
    #pragma unroll
    for (int m = 1; m < 64; m <<= 1) s += __shfl_xor(s, m, 64);
    const float mu = s * (1.0f / 256.0f);
    float q2 = 0.f, d;
    d = v.x - mu; q2 += d * d; d = v.y - mu; q2 += d * d;
    d = v.z - mu; q2 += d * d; d = v.w - mu; q2 += d * d;
    #pragma unroll
    for (int m = 1; m < 64; m <<= 1) q2 += __shfl_xor(q2, m, 64);
    const float rstd = rsqrtf(q2 * (1.0f / 256.0f) + 1e-5f);
    float4 gg = *(const float4*)(g + lane * 4);
    float4 bb = *(const float4*)(bt + lane * 4);
    u16x4 o;
    o[0] = f2bf((v.x - mu) * rstd * gg.x + bb.x);
    o[1] = f2bf((v.y - mu) * rstd * gg.y + bb.y);
    o[2] = f2bf((v.z - mu) * rstd * gg.z + bb.z);
    o[3] = f2bf((v.w - mu) * rstd * gg.w + bb.w);
    *(u16x4*)(out + (size_t)row * EE + lane * 4) = o;
}

// generic 16x16 MFMA GEMM tile: out = epi(A @ W + bias)
// EPI: 0=QKV pack (zsel: 0=Q A-layout, 1=K swz, 2=V swz), 1=residual +=,
//      2=gelu->bf16, 3=relu->bf16, 4=emb->fp32
template<int KP, int EPI>
__device__ __forceinline__ void gemm_core(
    const unsigned short* __restrict__ A, const unsigned short* __restrict__ WT,
    const float* __restrict__ bias, void* out, int N, int mb, int nb, int zsel,
    const int* tokens, const float* temb, const float* pe)
{
    const int t = threadIdx.x;
    const int w = t >> 6, lane = t & 63;
    const int m0 = mb * 64 + w * 16;
    const int n0 = nb * 16;
    const int q = lane >> 4, li = lane & 15;
    const unsigned short* ap = A + (size_t)(m0 + li) * KP + q * 8;
    const unsigned short* bp = WT + ((size_t)q * N + n0 + li) * 8;
    f32x4 acc = {0.f, 0.f, 0.f, 0.f};
    for (int ks = 0; ks < KP / 32; ++ks) {
        bf16x8 av = *(const bf16x8*)(ap + ks * 32);
        bf16x8 bv = *(const bf16x8*)(bp + (size_t)ks * 32 * N);
        acc = __builtin_amdgcn_mfma_f32_16x16x32_bf16(av, bv, acc, 0, 0, 0);
    }
    const int colg = n0 + li;
    const float bb = bias[colg];
    const int rbase = m0 + q * 4;
    #pragma unroll
    for (int r = 0; r < 4; ++r) {
        const int row = rbase + r;
        float v = acc[r] + bb;
        if constexpr (EPI == 0) {
            int b = row >> 10, l = row & 1023;
            int h = colg >> 5, d = colg & 31;
            int bh = b * HH + h;
            unsigned short* op = (unsigned short*)out;
            if (zsel == 0)
                op[((size_t)bh * LL + l) * DD + d] = f2bf(v);
            else if (zsel == 1)
                op[(size_t)bh * 32768 + (size_t)(d >> 3) * 8192 + (size_t)l * 8 + (d & 7)] = f2bf(v);
            else
                op[(size_t)bh * 32768 + (size_t)(l >> 3) * 256 + (size_t)d * 8 + (l & 7)] = f2bf(v);
        } else if constexpr (EPI == 1) {
            float* op = (float*)out;
            op[(size_t)row * N + colg] += v;
        } else if constexpr (EPI == 2) {
            ((unsigned short*)out)[(size_t)row * N + colg] = f2bf(gelu_f(v));
        } else if constexpr (EPI == 3) {
            ((unsigned short*)out)[(size_t)row * N + colg] = f2bf(fmaxf(v, 0.f));
        } else {
            int tok = tokens[row];
            v += temb[(size_t)tok * EE + colg] + pe[(size_t)(row & 1023) * EE + colg];
            ((float*)out)[(size_t)row * EE + colg] = v;
        }
    }
}

// flash-attention partial over one 256-wide m-chunk (zero block barriers)
__device__ __forceinline__ void attn_item(const Params& P, const float* gate_l,
                                          int it, void* SMv)
{
    unsigned short (*Pbuf)[16][72] = (unsigned short (*)[16][72])SMv;
    const int t = threadIdx.x;
    const int wq = t >> 6, lane = t & 63;
    const int li = lane & 15, qd = lane >> 4;
    const int b = it >> 9, h = (it >> 6) & 7;
    const int xx = it & 63;
    const int qt = xx & 15, mc = xx >> 4;
    const int bh = b * HH + h;
    const int q0 = qt * 64 + wq * 16;
    const int mbase = mc * 256;
    const float gh = gate_l[h];

    const bf16x8 qfrag = *(const bf16x8*)(P.qb16 + ((size_t)bh * LL + q0 + li) * DD + qd * 8);
    const unsigned short* kbase = P.kswz + (size_t)bh * 32768 + (size_t)qd * 8192 + (size_t)li * 8;
    const unsigned short* vbase = P.vswz + (size_t)bh * 32768 + (size_t)qd * 256 + (size_t)li * 8;
    const float* bp0 = P.bias + ((size_t)bh * LL + q0 + qd * 4) * LL + li;
    const float* mkp = P.mask + (size_t)b * LL + li;

    float mrun[4], lrun[4];
    f32x4 o0 = {0.f, 0.f, 0.f, 0.f}, o1 = {0.f, 0.f, 0.f, 0.f};
    #pragma unroll
    for (int r = 0; r < 4; ++r) { mrun[r] = -3.0e38f; lrun[r] = 0.f; }

    float bpre[4][4], kbpre[4];
    #pragma unroll
    for (int ms = 0; ms < 4; ++ms) {
        kbpre[ms] = mkp[mbase + ms * 16];
        #pragma unroll
        for (int r = 0; r < 4; ++r) bpre[ms][r] = bp0[(size_t)r * LL + mbase + ms * 16];
    }

    for (int mtt = 0; mtt < 4; ++mtt) {
        const int m0 = mbase + mtt * 64;
        f32x4 S[4];
        #pragma unroll
        for (int ms = 0; ms < 4; ++ms) {
            bf16x8 kf = *(const bf16x8*)(kbase + (size_t)(m0 + ms * 16) * 8);
            f32x4 z = {0.f, 0.f, 0.f, 0.f};
            S[ms] = __builtin_amdgcn_mfma_f32_16x16x32_bf16(qfrag, kf, z, 0, 0, 0);
        }
        float bc[4][4], kbc[4];
        #pragma unroll
        for (int ms = 0; ms < 4; ++ms) {
            kbc[ms] = (1.0f - kbpre[ms]) * (-10000.0f);
            #pragma unroll
            for (int r = 0; r < 4; ++r) bc[ms][r] = bpre[ms][r];
        }
        if (mtt < 3) {
            #pragma unroll
            for (int ms = 0; ms < 4; ++ms) {
                kbpre[ms] = mkp[m0 + 64 + ms * 16];
                #pragma unroll
                for (int r = 0; r < 4; ++r) bpre[ms][r] = bp0[(size_t)r * LL + m0 + 64 + ms * 16];
            }
        }
        float lg[4][4];
        #pragma unroll
        for (int ms = 0; ms < 4; ++ms)
            #pragma unroll
            for (int r = 0; r < 4; ++r)
                lg[ms][r] = fmaf(S[ms][r], SCALEF, fmaf(gh, bc[ms][r], kbc[ms]));

        float rmax[4];
        #pragma unroll
        for (int r = 0; r < 4; ++r)
            rmax[r] = fmaxf(fmaxf(lg[0][r], lg[1][r]), fmaxf(lg[2][r], lg[3][r]));
        #pragma unroll
        for (int bit = 1; bit < 16; bit <<= 1) {
            #pragma unroll
            for (int r = 0; r < 4; ++r) rmax[r] = fmaxf(rmax[r], __shfl_xor(rmax[r], bit, 64));
        }
        float alpha[4], rsum[4];
        #pragma unroll
        for (int r = 0; r < 4; ++r) {
            float nm = fmaxf(mrun[r], rmax[r]);
            alpha[r] = expf(mrun[r] - nm);
            mrun[r] = nm;
        }
        float p[4][4];
        #pragma unroll
        for (int r = 0; r < 4; ++r) rsum[r] = 0.f;
        #pragma unroll
        for (int ms = 0; ms < 4; ++ms)
            #pragma unroll
            for (int r = 0; r < 4; ++r) {
                p[ms][r] = expf(lg[ms][r] - mrun[r]);
                rsum[r] += p[ms][r];
            }
        #pragma unroll
        for (int bit = 1; bit < 16; bit <<= 1) {
            #pragma unroll
            for (int r = 0; r < 4; ++r) rsum[r] += __shfl_xor(rsum[r], bit, 64);
        }
        #pragma unroll
        for (int r = 0; r < 4; ++r) lrun[r] = lrun[r] * alpha[r] + rsum[r];
        #pragma unroll
        for (int r = 0; r < 4; ++r) { o0[r] *= alpha[r]; o1[r] *= alpha[r]; }
        #pragma unroll
        for (int ms = 0; ms < 4; ++ms)
            #pragma unroll
            for (int r = 0; r < 4; ++r)
                Pbuf[wq][qd * 4 + r][ms * 16 + li] = f2bf(p[ms][r]);
        #pragma unroll
        for (int c = 0; c < 2; ++c) {
            bf16x8 pa = *(const bf16x8*)&Pbuf[wq][li][c * 32 + qd * 8];
            bf16x8 vf0 = *(const bf16x8*)(vbase + (size_t)((m0 >> 3) + c * 4) * 256);
            bf16x8 vf1 = *(const bf16x8*)(vbase + (size_t)((m0 >> 3) + c * 4) * 256 + 16 * 8);
            o0 = __builtin_amdgcn_mfma_f32_16x16x32_bf16(pa, vf0, o0, 0, 0, 0);
            o1 = __builtin_amdgcn_mfma_f32_16x16x32_bf16(pa, vf1, o1, 0, 0, 0);
        }
    }
    const size_t rowg0 = (size_t)(mc * 2 + b) * LL;
    #pragma unroll
    for (int r = 0; r < 4; ++r) {
        const int row = q0 + qd * 4 + r;
        const size_t rg = rowg0 + row;
        P.Opart[rg * EE + h * DD + li]      = o0[r];
        P.Opart[rg * EE + h * DD + 16 + li] = o1[r];
        if (li == 0) {
            P.statsM[rg * HH + h] = mrun[r];
            P.statsL[rg * HH + h] = lrun[r];
        }
    }
}

__device__ __forceinline__ void merge_item(const Params& P, int row) {
    const int e = threadIdx.x;
    const int h = e >> 5;
    float m_[4];
    float M = -3.0e38f;
    #pragma unroll
    for (int mc = 0; mc < 4; ++mc) {
        m_[mc] = P.statsM[((size_t)mc * 2048 + row) * HH + h];
        M = fmaxf(M, m_[mc]);
    }
    float Lsum = 0.f, V = 0.f;
    #pragma unroll
    for (int mc = 0; mc < 4; ++mc) {
        float sc = expf(m_[mc] - M);
        Lsum = fmaf(P.statsL[((size_t)mc * 2048 + row) * HH + h], sc, Lsum);
        V = fmaf(P.Opart[((size_t)mc * 2048 + row) * EE + e], sc, V);
    }
    const float mq = P.mask[row];
    const float r = (Lsum > 0.f ? V / Lsum : 0.f) * mq * mq;
    P.aob[(size_t)row * EE + e] = f2bf(r);
}

__device__ __forceinline__ void pool_item(const Params& P, int it) {
    const int ch = it & 15, b = it >> 4, t = threadIdx.x;
    const int l0 = ch * 64;
    float s = 0.f, ms = 0.f;
    #pragma unroll 4
    for (int i = 0; i < 64; ++i) {
        int l = l0 + i;
        float mm = P.mask[b * LL + l];
        s = fmaf(P.x[((size_t)(b * LL + l)) * EE + t], mm, s);
        ms += mm;
    }
    P.part[(size_t)(b * 16 + ch) * EE + t] = s;
    if (t == 0) P.pmask[b * 16 + ch] = ms;
}

__device__ __forceinline__ void head_item(const Params& P, int b, void* SMv) {
    float* pn  = (float*)SMv;              // [256]
    float* red = pn + EE;                  // [4]
    float* wred = red + 4;                 // [4][NCN]
    const int t = threadIdx.x;
    const int wv = t >> 6, lane = t & 63;

    float v = 0.f, msum = 0.f;
    #pragma unroll
    for (int c = 0; c < 16; ++c) {
        v += P.part[(size_t)(b * 16 + c) * EE + t];
        msum += P.pmask[b * 16 + c];
    }
    v = v / fmaxf(msum, 1.0f);
    float s = v;
    #pragma unroll
    for (int mm = 1; mm < 64; mm <<= 1) s += __shfl_xor(s, mm, 64);
    if (lane == 0) red[wv] = s;
    __syncthreads();
    const float mu = (red[0] + red[1] + red[2] + red[3]) * (1.0f / 256.0f);
    __syncthreads();
    float d = v - mu;
    float q2 = d * d;
    #pragma unroll
    for (int mm = 1; mm < 64; mm <<= 1) q2 += __shfl_xor(q2, mm, 64);
    if (lane == 0) red[wv] = q2;
    __syncthreads();
    const float var = (red[0] + red[1] + red[2] + red[3]) * (1.0f / 256.0f);
    const float rstd = rsqrtf(var + 1e-5f);
    pn[t] = d * rstd * P.hlng[t] + P.hlnb[t];
    __syncthreads();
    float acc = P.hb1[t];
    #pragma unroll 8
    for (int k = 0; k < EE; ++k) acc = fmaf(pn[k], P.hw1[k * EE + t], acc);
    const float g = gelu_f(acc);
    float contrib[NCN];
    #pragma unroll
    for (int cc = 0; cc < NCN; ++cc) contrib[cc] = g * P.hw2[(size_t)t * NCN + cc];
    #pragma unroll
    for (int mm = 1; mm < 64; mm <<= 1) {
        #pragma unroll
        for (int cc = 0; cc < NCN; ++cc) contrib[cc] += __shfl_xor(contrib[cc], mm, 64);
    }
    if (lane == 0) {
        #pragma unroll
        for (int cc = 0; cc < NCN; ++cc) wred[wv * NCN + cc] = contrib[cc];
    }
    __syncthreads();
    if (t < NCN)
        P.outp[b * NCN + t] = P.hb2[t] + wred[0 * NCN + t] + wred[1 * NCN + t]
                            + wred[2 * NCN + t] + wred[3 * NCN + t];
}

// ---------------------------------------------------------------------------
// the mega-kernel: whole forward pass, one dispatch, 20 grid barriers
// ---------------------------------------------------------------------------
__global__ __launch_bounds__(256, 2) void mega(Params P)
{
    __shared__ __align__(16) unsigned char SM[12288];
    const int bid = blockIdx.x;
    unsigned* cnt = P.cnt;

    // P0: weight prep (1848 items) + pairwise gather (2048 items)
    for (int it = bid; it < 1848 + 2048; it += GRID) {
        if (it < 1848) prep_item(P, it);
        else           gather_item(P, it - 1848);
    }
    gbar(cnt++);

    // pair MLP1: relu(flat @ w1 + b1) -> ph   (512 items)
    gemm_core<KP1, 3>(P.flat, P.wt + OFF_PW1, P.pb1, P.ph, EE,
                      bid & 31, bid >> 5, 0, nullptr, nullptr, nullptr);
    gbar(cnt++);

    // pair MLP2 + emb -> x fp32  (512 items)
    gemm_core<EE, 4>(P.ph, P.wt + OFF_PW2, P.pb2, P.x, EE,
                     bid & 31, bid >> 5, 0, P.tokens, P.temb, P.pe);
    gbar(cnt++);

    for (int i = 0; i < NLAYER; ++i) {
        // LN1 -> xn (512 items)
        ln_item(P.x, P.ln1g + i * EE, P.ln1b + i * EE, P.xn, bid);
        gbar(cnt++);
        // QKV (1536 items)
        for (int it = bid; it < 1536; it += GRID) {
            const int z = it >> 9, rem = it & 511;
            const unsigned short* W = P.wt + OFF_QKVO + (size_t)(i * 4 + z) * 65536;
            const float* bb = (z == 0 ? P.bq : z == 1 ? P.bk : P.bv) + i * EE;
            void* out = (z == 0) ? (void*)P.qb16 : (z == 1) ? (void*)P.kswz : (void*)P.vswz;
            gemm_core<EE, 0>(P.xn, W, bb, out, EE, rem & 31, rem >> 5, z,
                             nullptr, nullptr, nullptr);
        }
        gbar(cnt++);
        // attention partials (1024 items)
        for (int it = bid; it < 1024; it += GRID)
            attn_item(P, P.gate + i * HH, it, SM);
        gbar(cnt++);
        // merge (2048 items)
        for (int it = bid; it < 2048; it += GRID)
            merge_item(P, it);
        gbar(cnt++);
        // O-proj + residual (512 items)
        gemm_core<EE, 1>(P.aob, P.wt + OFF_QKVO + (size_t)(i * 4 + 3) * 65536,
                         P.bo + i * EE, P.x, EE, bid & 31, bid >> 5, 0,
                         nullptr, nullptr, nullptr);
        gbar(cnt++);
        // LN2 -> xn (512 items)
        ln_item(P.x, P.ln2g + i * EE, P.ln2b + i * EE, P.xn, bid);
        gbar(cnt++);
        // FFN1 (1024 items)
        for (int it = bid; it < 1024; it += GRID)
            gemm_core<EE, 2>(P.xn, P.wt + OFF_FW1 + (size_t)i * 131072,
                             P.fb1 + i * HIDN, P.ffh, HIDN, it & 31, it >> 5, 0,
                             nullptr, nullptr, nullptr);
        gbar(cnt++);
        // FFN2 (512 items)
        gemm_core<HIDN, 1>(P.ffh, P.wt + OFF_FW2 + (size_t)i * 131072,
                           P.fb2 + i * EE, P.x, EE, bid & 31, bid >> 5, 0,
                           nullptr, nullptr, nullptr);
        gbar(cnt++);
    }

    // pool partials (32 items)
    if (bid < 32) pool_item(P, bid);
    gbar(cnt++);
    // head (2 items)
    if (bid < BB) head_item(P, bid, SM);
}

// ---------------------------------------------------------------------------
extern "C" void kernel_launch(void* const* d_in, const int* in_sizes, int n_in,
                              void* d_out, int out_size, void* d_ws, size_t ws_size,
                              hipStream_t stream) {
    Params P;
    P.tokens = (const int*)  d_in[0];
    P.xp     = (const float*)d_in[1];
    P.bias   = (const float*)d_in[2];
    P.mask   = (const float*)d_in[3];
    P.temb   = (const float*)d_in[4];
    P.pe     = (const float*)d_in[5];
    const float* pw1 = (const float*)d_in[6];
    P.pb1    = (const float*)d_in[7];
    const float* pw2 = (const float*)d_in[8];
    P.pb2    = (const float*)d_in[9];
    P.ln1g   = (const float*)d_in[10];
    P.ln1b   = (const float*)d_in[11];
    const float* wq = (const float*)d_in[12];
    const float* wk = (const float*)d_in[13];
    const float* wv = (const float*)d_in[14];
    const float* wo = (const float*)d_in[15];
    P.bq     = (const float*)d_in[16];
    P.bk     = (const float*)d_in[17];
    P.bv     = (const float*)d_in[18];
    P.bo     = (const float*)d_in[19];
    P.gate   = (const float*)d_in[20];
    P.ln2g   = (const float*)d_in[21];
    P.ln2b   = (const float*)d_in[22];
    const float* fw1 = (const float*)d_in[23];
    P.fb1    = (const float*)d_in[24];
    const float* fw2 = (const float*)d_in[25];
    P.fb2    = (const float*)d_in[26];
    P.hlng   = (const float*)d_in[27];
    P.hlnb   = (const float*)d_in[28];
    P.hw1    = (const float*)d_in[29];
    P.hb1    = (const float*)d_in[30];
    P.hw2    = (const float*)d_in[31];
    P.hb2    = (const float*)d_in[32];
    P.outp   = (float*)d_out;

    // ------ workspace layout ------
    float* ws = (float*)d_ws;
    const size_t NTOK = (size_t)BB * LL * EE;                 // 524288
    P.x      = ws;                                            // fp32 [2048][256]
    P.Opart  = ws + NTOK;                                     // fp32 [4][2048][256]
    P.statsM = P.Opart + 4 * NTOK;                            // [4][2048][8]
    P.statsL = P.statsM + 65536;
    P.part   = P.statsL + 65536;                              // [2][16][256]
    P.pmask  = P.part + 32 * EE;                              // [32]
    unsigned short* usp = (unsigned short*)(P.pmask + 32);
    usp = (unsigned short*)(((size_t)usp + 15) & ~(size_t)15);
    P.qb16 = usp;                                             // bf16 [BH][L][32]
    P.kswz = P.qb16 + NTOK;                                   // bf16 [BH][4][1024][8]
    P.vswz = P.kswz + NTOK;                                   // bf16 [BH][128][32][8]
    P.xn   = P.vswz + NTOK;                                   // bf16 [2048][256]
    P.aob  = P.xn + NTOK;                                     // bf16 [2048][256]
    P.ffh  = P.aob + NTOK;                                    // bf16 [2048][512]
    P.ph   = P.ffh + (size_t)BB * LL * HIDN;                  // bf16 [2048][256]
    P.flat = P.ph + NTOK;                                     // bf16 [2048][1056]
    P.wt   = P.flat + (size_t)BB * LL * KP1;                  // weight pool
    unsigned short* wt_end = P.wt + (OFF_FW2 + 2 * 131072);
    P.cnt  = (unsigned*)(((size_t)wt_end + 7) & ~(size_t)7);  // 32 barrier counters

    // prep descriptors
    P.pd.src[0] = pw1;  P.pd.K[0] = INPAIR; P.pd.N[0] = EE;  P.pd.dst[0] = OFF_PW1;
    P.pd.src[1] = pw2;  P.pd.K[1] = EE;     P.pd.N[1] = EE;  P.pd.dst[1] = OFF_PW2;
    for (int l = 0; l < 2; ++l) {
        const float* srcs[4] = {wq + l * EE * EE, wk + l * EE * EE,
                                wv + l * EE * EE, wo + l * EE * EE};
        for (int wch = 0; wch < 4; ++wch) {
            int mi = 2 + l * 4 + wch;
            P.pd.src[mi] = srcs[wch]; P.pd.K[mi] = EE; P.pd.N[mi] = EE;
            P.pd.dst[mi] = OFF_QKVO + (size_t)(l * 4 + wch) * 65536;
        }
    }
    for (int l = 0; l < 2; ++l) {
        P.pd.src[10 + l] = fw1 + (size_t)l * EE * HIDN;
        P.pd.K[10 + l] = EE;  P.pd.N[10 + l] = HIDN;
        P.pd.dst[10 + l] = OFF_FW1 + (size_t)l * 131072;
        P.pd.src[12 + l] = fw2 + (size_t)l * HIDN * EE;
        P.pd.K[12 + l] = HIDN; P.pd.N[12 + l] = EE;
        P.pd.dst[12 + l] = OFF_FW2 + (size_t)l * 131072;
    }

    // zero barrier counters (stream-ordered, graph-capture safe), then launch
    hipMemsetAsync(P.cnt, 0, 32 * sizeof(unsigned), stream);
    mega<<<dim3(GRID), dim3(256), 0, stream>>>(P);

    (void)in_sizes; (void)n_in; (void)out_size; (void)ws_size;
}

// Round 8
// 338.807 us; speedup vs baseline: 7.3298x; 7.3298x over previous
//
#include <hip/hip_runtime.h>
#include <math.h>

// Problem constants (fixed by the reference)
#define BB     2
#define LL     1024
#define CC     4
#define EE     256
#define HH     8
#define DD     32
#define NLAYER 2
#define W1N    257          // WIN+1
#define INPAIR 1028         // C*(WIN+1)
#define KP1    1056         // INPAIR padded to 32
#define HIDN   512
#define NCN    10
#define SCALEF 0.17677669529663687f   // 32^-0.5

typedef short bf16x8 __attribute__((ext_vector_type(8)));
typedef float f32x4  __attribute__((ext_vector_type(4)));
typedef unsigned short u16x4 __attribute__((ext_vector_type(4)));
typedef unsigned short u16x8 __attribute__((ext_vector_type(8)));

__device__ __forceinline__ float gelu_f(float x) {
    return 0.5f * x * (1.0f + erff(x * 0.7071067811865475f));
}
__device__ __forceinline__ unsigned short f2bf(float f) {
    unsigned u = __float_as_uint(f);
    u += 0x7fffu + ((u >> 16) & 1u);      // RNE
    return (unsigned short)(u >> 16);
}

// ---------------------------------------------------------------------------
// prep_gather: one launch for both weight conversion and the pairwise gather.
//  blocks [0,1848): weight W[K][N] fp32 -> WT bf16 swizzled [(k>>3)][n][k&7]
//  blocks [1848, 1848+2048): diagonal-window gather -> flat bf16 [2048][1056]
// ---------------------------------------------------------------------------
struct PrepDesc {
    const float* src[14];
    int K[14];
    int N[14];
    unsigned long long dst[14];
};

__global__ __launch_bounds__(256) void prep_gather(
    PrepDesc pd, unsigned short* __restrict__ wt,
    const float* __restrict__ xp, unsigned short* __restrict__ flat)
{
    const int bid = blockIdx.x;
    if (bid < 1848) {
        const int mi = bid / 132, k8 = bid - mi * 132;
        const int K = pd.K[mi], N = pd.N[mi];
        const int Kp = (K + 31) & ~31;
        if (k8 * 8 >= Kp) return;
        const float* src = pd.src[mi];
        unsigned short* dst = wt + pd.dst[mi];
        for (int n = threadIdx.x; n < N; n += 256) {
            u16x8 o;
            #pragma unroll
            for (int j = 0; j < 8; ++j) {
                int k = k8 * 8 + j;
                float v = (k < K) ? src[(size_t)k * N + n] : 0.f;
                o[j] = f2bf(v);
            }
            *(u16x8*)(dst + ((size_t)k8 * N + n) * 8) = o;
        }
    } else {
        const int row = bid - 1848;
        const int b = row >> 10, l = row & 1023;
        const float* base = xp + (size_t)b * CC * LL * LL + (size_t)l * LL;
        for (int kp = threadIdx.x; kp < KP1; kp += 256) {
            float v = 0.f;
            if (kp < INPAIR) {
                int c = kp / W1N;
                int w = kp - c * W1N;
                int col = l + w - 128;
                if (col >= 0 && col < LL) v = base[(size_t)c * LL * LL + col];
            }
            flat[(size_t)row * KP1 + kp] = f2bf(v);
        }
    }
}

// ---------------------------------------------------------------------------
// ln_bf16: per-row LayerNorm of fp32 x -> bf16 out. 1 wave per row.
// ---------------------------------------------------------------------------
__global__ __launch_bounds__(256) void ln_bf16(
    const float* __restrict__ x, const float* __restrict__ g,
    const float* __restrict__ bt, unsigned short* __restrict__ out)
{
    const int row = blockIdx.x * 4 + (threadIdx.x >> 6);
    const int lane = threadIdx.x & 63;
    float4 v = *(const float4*)(x + (size_t)row * EE + lane * 4);
    float s = v.x + v.y + v.z + v.w;
    #pragma unroll
    for (int m = 1; m < 64; m <<= 1) s += __shfl_xor(s, m, 64);
    const float mu = s * (1.0f / 256.0f);
    float q2 = 0.f, d;
    d = v.x - mu; q2 += d * d; d = v.y - mu; q2 += d * d;
    d = v.z - mu; q2 += d * d; d = v.w - mu; q2 += d * d;
    #pragma unroll
    for (int m = 1; m < 64; m <<= 1) q2 += __shfl_xor(q2, m, 64);
    const float rstd = rsqrtf(q2 * (1.0f / 256.0f) + 1e-5f);
    float4 gg = *(const float4*)(g + lane * 4);
    float4 bb = *(const float4*)(bt + lane * 4);
    u16x4 o;
    o[0] = f2bf((v.x - mu) * rstd * gg.x + bb.x);
    o[1] = f2bf((v.y - mu) * rstd * gg.y + bb.y);
    o[2] = f2bf((v.z - mu) * rstd * gg.z + bb.z);
    o[3] = f2bf((v.w - mu) * rstd * gg.w + bb.w);
    *(u16x4*)(out + (size_t)row * EE + lane * 4) = o;
}

// ---------------------------------------------------------------------------
// gemm_mfma: out = epi(A_bf16 @ W + bias). No LDS, no barriers.
// A [2048][KP] bf16 row-major; WT swizzled bf16 (prep layout).
// Block 256 thr = 4 waves; wave = 16x16 tile. Grid (32, N/16, z).
// EPI: 0=QKV pack (z: 0=Q A-layout bf16, 1=K swz, 2=V swz)
//      1=residual +=, 2=gelu->bf16, 3=relu->bf16, 4=emb->fp32
// ---------------------------------------------------------------------------
template<int KP, int EPI>
__global__ __launch_bounds__(256) void gemm_mfma(
    const unsigned short* __restrict__ A,
    const unsigned short* wt0, const float* b0, void* o0,
    const unsigned short* wt1, const float* b1, void* o1,
    const unsigned short* wt2, const float* b2, void* o2,
    int N,
    const int* __restrict__ tokens, const float* __restrict__ temb,
    const float* __restrict__ pe)
{
    const int t = threadIdx.x;
    const int w = t >> 6, lane = t & 63;
    const int m0 = blockIdx.x * 64 + w * 16;
    const int n0 = blockIdx.y * 16;
    const unsigned short* WT; const float* bias; void* out;
    if (blockIdx.z == 0)      { WT = wt0; bias = b0; out = o0; }
    else if (blockIdx.z == 1) { WT = wt1; bias = b1; out = o1; }
    else                      { WT = wt2; bias = b2; out = o2; }

    const int q = lane >> 4, li = lane & 15;
    const unsigned short* ap = A + (size_t)(m0 + li) * KP + q * 8;
    const unsigned short* bp = WT + ((size_t)q * N + n0 + li) * 8;
    f32x4 acc = {0.f, 0.f, 0.f, 0.f};
    for (int ks = 0; ks < KP / 32; ++ks) {
        bf16x8 av = *(const bf16x8*)(ap + ks * 32);
        bf16x8 bv = *(const bf16x8*)(bp + (size_t)ks * 32 * N);
        acc = __builtin_amdgcn_mfma_f32_16x16x32_bf16(av, bv, acc, 0, 0, 0);
    }

    const int colg = n0 + li;
    const float bb = bias[colg];
    const int rbase = m0 + q * 4;
    #pragma unroll
    for (int r = 0; r < 4; ++r) {
        const int row = rbase + r;
        float v = acc[r] + bb;
        if constexpr (EPI == 0) {          // QKV -> bf16 attention layouts
            int b = row >> 10, l = row & 1023;
            int h = colg >> 5, d = colg & 31;
            int bh = b * HH + h;
            unsigned short* op = (unsigned short*)out;
            if (blockIdx.z == 0)
                op[((size_t)bh * LL + l) * DD + d] = f2bf(v);
            else if (blockIdx.z == 1)
                op[(size_t)bh * 32768 + (size_t)(d >> 3) * 8192 + (size_t)l * 8 + (d & 7)] = f2bf(v);
            else
                op[(size_t)bh * 32768 + (size_t)(l >> 3) * 256 + (size_t)d * 8 + (l & 7)] = f2bf(v);
        } else if constexpr (EPI == 1) {   // residual accumulate into fp32 out
            float* op = (float*)out;
            op[(size_t)row * N + colg] += v;
        } else if constexpr (EPI == 2) {   // gelu -> bf16
            ((unsigned short*)out)[(size_t)row * N + colg] = f2bf(gelu_f(v));
        } else if constexpr (EPI == 3) {   // relu -> bf16
            ((unsigned short*)out)[(size_t)row * N + colg] = f2bf(fmaxf(v, 0.f));
        } else {                            // emb: + temb[tok] + pe -> fp32
            int tok = tokens[row];
            v += temb[(size_t)tok * EE + colg] + pe[(size_t)(row & 1023) * EE + colg];
            ((float*)out)[(size_t)row * EE + colg] = v;
        }
    }
}

// ---------------------------------------------------------------------------
// attn_part_mfma: flash attention partial over a 256-wide m-chunk, MFMA,
// zero barriers. Block = 256 thr (4 waves), wave = 16 q-rows.
// Grid (16 qt | 4 mc in x, H, B) = 1024 blocks.
// ---------------------------------------------------------------------------
__global__ __launch_bounds__(256, 4) void attn_part_mfma(
    const unsigned short* __restrict__ qb,
    const unsigned short* __restrict__ kswz,
    const unsigned short* __restrict__ vswz,
    const float* __restrict__ bias, const float* __restrict__ mask,
    const float* __restrict__ gate,
    float* __restrict__ Opart, float* __restrict__ statsM,
    float* __restrict__ statsL)
{
    __shared__ unsigned short Pbuf[4][16][72];   // per-wave [16 q][64 m] (+8 pad)
    const int t = threadIdx.x;
    const int wq = t >> 6, lane = t & 63;
    const int li = lane & 15, qd = lane >> 4;
    const int h = blockIdx.y, b = blockIdx.z;
    const int bh = b * HH + h;
    const int qt = blockIdx.x & 15, mc = blockIdx.x >> 4;
    const int q0 = qt * 64 + wq * 16;
    const int mbase = mc * 256;
    const float gh = gate[h];

    const bf16x8 qfrag = *(const bf16x8*)(qb + ((size_t)bh * LL + q0 + li) * DD + qd * 8);

    const unsigned short* kbase = kswz + (size_t)bh * 32768 + (size_t)qd * 8192 + (size_t)li * 8;
    const unsigned short* vbase = vswz + (size_t)bh * 32768 + (size_t)qd * 256 + (size_t)li * 8;
    const float* bp0 = bias + ((size_t)bh * LL + q0 + qd * 4) * LL + li;
    const float* mkp = mask + (size_t)b * LL + li;

    float mrun[4], lrun[4];
    f32x4 o0 = {0.f, 0.f, 0.f, 0.f}, o1 = {0.f, 0.f, 0.f, 0.f};
    #pragma unroll
    for (int r = 0; r < 4; ++r) { mrun[r] = -3.0e38f; lrun[r] = 0.f; }

    float bpre[4][4], kbpre[4];
    #pragma unroll
    for (int ms = 0; ms < 4; ++ms) {
        kbpre[ms] = mkp[mbase + ms * 16];
        #pragma unroll
        for (int r = 0; r < 4; ++r) bpre[ms][r] = bp0[(size_t)r * LL + mbase + ms * 16];
    }

    for (int mtt = 0; mtt < 4; ++mtt) {
        const int m0 = mbase + mtt * 64;
        f32x4 S[4];
        #pragma unroll
        for (int ms = 0; ms < 4; ++ms) {
            bf16x8 kf = *(const bf16x8*)(kbase + (size_t)(m0 + ms * 16) * 8);
            f32x4 z = {0.f, 0.f, 0.f, 0.f};
            S[ms] = __builtin_amdgcn_mfma_f32_16x16x32_bf16(qfrag, kf, z, 0, 0, 0);
        }
        float bc[4][4], kbc[4];
        #pragma unroll
        for (int ms = 0; ms < 4; ++ms) {
            kbc[ms] = (1.0f - kbpre[ms]) * (-10000.0f);
            #pragma unroll
            for (int r = 0; r < 4; ++r) bc[ms][r] = bpre[ms][r];
        }
        if (mtt < 3) {
            #pragma unroll
            for (int ms = 0; ms < 4; ++ms) {
                kbpre[ms] = mkp[m0 + 64 + ms * 16];
                #pragma unroll
                for (int r = 0; r < 4; ++r) bpre[ms][r] = bp0[(size_t)r * LL + m0 + 64 + ms * 16];
            }
        }
        float lg[4][4];
        #pragma unroll
        for (int ms = 0; ms < 4; ++ms)
            #pragma unroll
            for (int r = 0; r < 4; ++r)
                lg[ms][r] = fmaf(S[ms][r], SCALEF, fmaf(gh, bc[ms][r], kbc[ms]));

        float rmax[4];
        #pragma unroll
        for (int r = 0; r < 4; ++r)
            rmax[r] = fmaxf(fmaxf(lg[0][r], lg[1][r]), fmaxf(lg[2][r], lg[3][r]));
        #pragma unroll
        for (int bit = 1; bit < 16; bit <<= 1) {
            #pragma unroll
            for (int r = 0; r < 4; ++r) rmax[r] = fmaxf(rmax[r], __shfl_xor(rmax[r], bit, 64));
        }
        float alpha[4], rsum[4];
        #pragma unroll
        for (int r = 0; r < 4; ++r) {
            float nm = fmaxf(mrun[r], rmax[r]);
            alpha[r] = expf(mrun[r] - nm);
            mrun[r] = nm;
        }
        float p[4][4];
        #pragma unroll
        for (int r = 0; r < 4; ++r) rsum[r] = 0.f;
        #pragma unroll
        for (int ms = 0; ms < 4; ++ms)
            #pragma unroll
            for (int r = 0; r < 4; ++r) {
                p[ms][r] = expf(lg[ms][r] - mrun[r]);
                rsum[r] += p[ms][r];
            }
        #pragma unroll
        for (int bit = 1; bit < 16; bit <<= 1) {
            #pragma unroll
            for (int r = 0; r < 4; ++r) rsum[r] += __shfl_xor(rsum[r], bit, 64);
        }
        #pragma unroll
        for (int r = 0; r < 4; ++r) lrun[r] = lrun[r] * alpha[r] + rsum[r];
        #pragma unroll
        for (int r = 0; r < 4; ++r) { o0[r] *= alpha[r]; o1[r] *= alpha[r]; }
        #pragma unroll
        for (int ms = 0; ms < 4; ++ms)
            #pragma unroll
            for (int r = 0; r < 4; ++r)
                Pbuf[wq][qd * 4 + r][ms * 16 + li] = f2bf(p[ms][r]);
        #pragma unroll
        for (int c = 0; c < 2; ++c) {
            bf16x8 pa = *(const bf16x8*)&Pbuf[wq][li][c * 32 + qd * 8];
            bf16x8 vf0 = *(const bf16x8*)(vbase + (size_t)((m0 >> 3) + c * 4) * 256);
            bf16x8 vf1 = *(const bf16x8*)(vbase + (size_t)((m0 >> 3) + c * 4) * 256 + 16 * 8);
            o0 = __builtin_amdgcn_mfma_f32_16x16x32_bf16(pa, vf0, o0, 0, 0, 0);
            o1 = __builtin_amdgcn_mfma_f32_16x16x32_bf16(pa, vf1, o1, 0, 0, 0);
        }
    }
    const size_t rowg0 = (size_t)(mc * 2 + b) * LL;
    #pragma unroll
    for (int r = 0; r < 4; ++r) {
        const int row = q0 + qd * 4 + r;
        const size_t rg = rowg0 + row;
        Opart[rg * EE + h * DD + li]      = o0[r];
        Opart[rg * EE + h * DD + 16 + li] = o1[r];
        if (li == 0) {
            statsM[rg * HH + h] = mrun[r];
            statsL[rg * HH + h] = lrun[r];
        }
    }
}

// ---------------------------------------------------------------------------
// attn_merge: combine 4 m-chunk partials -> aob bf16 [2048][256]
// ---------------------------------------------------------------------------
__global__ __launch_bounds__(256) void attn_merge(
    const float* __restrict__ Opart, const float* __restrict__ statsM,
    const float* __restrict__ statsL, const float* __restrict__ mask,
    unsigned short* __restrict__ aob)
{
    const int row = blockIdx.x;         // 0..2047 global row
    const int e = threadIdx.x;
    const int h = e >> 5;
    float m_[4];
    float M = -3.0e38f;
    #pragma unroll
    for (int mc = 0; mc < 4; ++mc) {
        m_[mc] = statsM[((size_t)mc * 2048 + row) * HH + h];
        M = fmaxf(M, m_[mc]);
    }
    float Lsum = 0.f, V = 0.f;
    #pragma unroll
    for (int mc = 0; mc < 4; ++mc) {
        float sc = expf(m_[mc] - M);
        Lsum = fmaf(statsL[((size_t)mc * 2048 + row) * HH + h], sc, Lsum);
        V = fmaf(Opart[((size_t)mc * 2048 + row) * EE + e], sc, V);
    }
    const float mq = mask[row];
    const float r = (Lsum > 0.f ? V / Lsum : 0.f) * mq * mq;
    aob[(size_t)row * EE + e] = f2bf(r);
}

// ---------------------------------------------------------------------------
// pool_head: masked mean pool + LN + gelu(W1) + W2, one 1024-thr block per b.
// (validated in R6)
// ---------------------------------------------------------------------------
__global__ __launch_bounds__(1024) void pool_head(
    const float* __restrict__ x, const float* __restrict__ mask,
    const float* __restrict__ hg, const float* __restrict__ hb,
    const float* __restrict__ w1, const float* __restrict__ b1,
    const float* __restrict__ w2, const float* __restrict__ b2,
    float* __restrict__ outp)
{
    __shared__ float psum[4][EE];
    __shared__ float msums[4];
    __shared__ float red[4];
    __shared__ float wred[4][NCN];
    __shared__ float pn[EE];
    const int b = blockIdx.x;
    const int t = threadIdx.x;
    const int col = t & 255, c = t >> 8;

    float s = 0.f, ms = 0.f;
    for (int i = 0; i < 256; ++i) {
        int l = c * 256 + i;
        float mm = mask[b * LL + l];
        s = fmaf(x[((size_t)b * LL + l) * EE + col], mm, s);
        ms += mm;
    }
    psum[c][col] = s;
    if (col == 0) msums[c] = ms;
    __syncthreads();

    float v = 0.f;
    const int wv = t >> 6, lane = t & 63;
    if (t < EE) {
        float tot = psum[0][t] + psum[1][t] + psum[2][t] + psum[3][t];
        float msum = msums[0] + msums[1] + msums[2] + msums[3];
        v = tot / fmaxf(msum, 1.0f);
        float sv = v;
        #pragma unroll
        for (int mm = 1; mm < 64; mm <<= 1) sv += __shfl_xor(sv, mm, 64);
        if (lane == 0) red[wv] = sv;
    }
    __syncthreads();
    const float mu = (red[0] + red[1] + red[2] + red[3]) * (1.0f / 256.0f);
    __syncthreads();
    if (t < EE) {
        float d = v - mu;
        float q2 = d * d;
        #pragma unroll
        for (int mm = 1; mm < 64; mm <<= 1) q2 += __shfl_xor(q2, mm, 64);
        if (lane == 0) red[wv] = q2;
    }
    __syncthreads();
    const float var = (red[0] + red[1] + red[2] + red[3]) * (1.0f / 256.0f);
    const float rstd = rsqrtf(var + 1e-5f);
    if (t < EE) pn[t] = (v - mu) * rstd * hg[t] + hb[t];
    __syncthreads();
    if (t < EE) {
        float acc = b1[t];
        #pragma unroll 8
        for (int k = 0; k < EE; ++k) acc = fmaf(pn[k], w1[k * EE + t], acc);
        const float g = gelu_f(acc);
        float contrib[NCN];
        #pragma unroll
        for (int cc = 0; cc < NCN; ++cc) contrib[cc] = g * w2[(size_t)t * NCN + cc];
        #pragma unroll
        for (int mm = 1; mm < 64; mm <<= 1) {
            #pragma unroll
            for (int cc = 0; cc < NCN; ++cc) contrib[cc] += __shfl_xor(contrib[cc], mm, 64);
        }
        if (lane == 0) {
            #pragma unroll
            for (int cc = 0; cc < NCN; ++cc) wred[wv][cc] = contrib[cc];
        }
    }
    __syncthreads();
    if (t < NCN)
        outp[b * NCN + t] = b2[t] + wred[0][t] + wred[1][t] + wred[2][t] + wred[3][t];
}

// ---------------------------------------------------------------------------
extern "C" void kernel_launch(void* const* d_in, const int* in_sizes, int n_in,
                              void* d_out, int out_size, void* d_ws, size_t ws_size,
                              hipStream_t stream) {
    const int*   tokens = (const int*)  d_in[0];
    const float* xp     = (const float*)d_in[1];
    const float* bias   = (const float*)d_in[2];
    const float* mask   = (const float*)d_in[3];
    const float* temb   = (const float*)d_in[4];
    const float* pe     = (const float*)d_in[5];
    const float* pw1    = (const float*)d_in[6];
    const float* pb1    = (const float*)d_in[7];
    const float* pw2    = (const float*)d_in[8];
    const float* pb2    = (const float*)d_in[9];
    const float* ln1g   = (const float*)d_in[10];
    const float* ln1b   = (const float*)d_in[11];
    const float* wq     = (const float*)d_in[12];
    const float* wk     = (const float*)d_in[13];
    const float* wv     = (const float*)d_in[14];
    const float* wo     = (const float*)d_in[15];
    const float* bq     = (const float*)d_in[16];
    const float* bk     = (const float*)d_in[17];
    const float* bv     = (const float*)d_in[18];
    const float* bo     = (const float*)d_in[19];
    const float* gate   = (const float*)d_in[20];
    const float* ln2g   = (const float*)d_in[21];
    const float* ln2b   = (const float*)d_in[22];
    const float* fw1    = (const float*)d_in[23];
    const float* fb1    = (const float*)d_in[24];
    const float* fw2    = (const float*)d_in[25];
    const float* fb2    = (const float*)d_in[26];
    const float* hlng   = (const float*)d_in[27];
    const float* hlnb   = (const float*)d_in[28];
    const float* hw1    = (const float*)d_in[29];
    const float* hb1    = (const float*)d_in[30];
    const float* hw2    = (const float*)d_in[31];
    const float* hb2    = (const float*)d_in[32];

    // ------ workspace layout ------
    float* ws = (float*)d_ws;
    const size_t NTOK = (size_t)BB * LL * EE;                 // 524288
    float* x      = ws;                                       // fp32 [2048][256]
    float* Opart  = ws + NTOK;                                // fp32 [4][2048][256]
    float* statsM = Opart + 4 * NTOK;                         // [4][2048][8]
    float* statsL = statsM + 65536;
    unsigned short* usp = (unsigned short*)(statsL + 65536);
    usp = (unsigned short*)(((size_t)usp + 15) & ~(size_t)15);
    unsigned short* qb16 = usp;                               // bf16 [BH][L][32]
    unsigned short* kswz = qb16 + NTOK;                       // bf16 [BH][4][1024][8]
    unsigned short* vswz = kswz + NTOK;                       // bf16 [BH][128][32][8]
    unsigned short* aob  = vswz + NTOK;                       // bf16 [2048][256]
    unsigned short* ffh  = aob + NTOK;                        // bf16 [2048][512]
    unsigned short* ph   = ffh + (size_t)BB * LL * HIDN;      // bf16 [2048][256]
    unsigned short* flat = ph + NTOK;                         // bf16 [2048][1056]
    unsigned short* wt   = flat + (size_t)BB * LL * KP1;      // weight pool

    // weight-pool sub-offsets (ushort units)
    const size_t OFF_PW1 = 0;                         // 1056*256 = 270336
    const size_t OFF_PW2 = 270336;                    // 65536
    const size_t OFF_QKVO = 335872;                   // 8 * 65536
    const size_t OFF_FW1 = 860160;                    // 2 * 131072
    const size_t OFF_FW2 = 1122304;                   // 2 * 131072

    // ------ prep descriptors ------
    PrepDesc pd;
    pd.src[0] = pw1;  pd.K[0] = INPAIR; pd.N[0] = EE;  pd.dst[0] = OFF_PW1;
    pd.src[1] = pw2;  pd.K[1] = EE;     pd.N[1] = EE;  pd.dst[1] = OFF_PW2;
    for (int l = 0; l < 2; ++l) {
        const float* srcs[4] = {wq + l * EE * EE, wk + l * EE * EE,
                                wv + l * EE * EE, wo + l * EE * EE};
        for (int wch = 0; wch < 4; ++wch) {
            int mi = 2 + l * 4 + wch;
            pd.src[mi] = srcs[wch]; pd.K[mi] = EE; pd.N[mi] = EE;
            pd.dst[mi] = OFF_QKVO + (size_t)(l * 4 + wch) * 65536;
        }
    }
    for (int l = 0; l < 2; ++l) {
        pd.src[10 + l] = fw1 + (size_t)l * EE * HIDN;
        pd.K[10 + l] = EE;  pd.N[10 + l] = HIDN;
        pd.dst[10 + l] = OFF_FW1 + (size_t)l * 131072;
        pd.src[12 + l] = fw2 + (size_t)l * HIDN * EE;
        pd.K[12 + l] = HIDN; pd.N[12 + l] = EE;
        pd.dst[12 + l] = OFF_FW2 + (size_t)l * 131072;
    }

    // ------ weight prep + pairwise gather (one launch) ------
    prep_gather<<<dim3(1848 + 2048), dim3(256), 0, stream>>>(pd, wt, xp, flat);

    // MLP1: relu(flat @ w1 + b1) -> ph (bf16)
    gemm_mfma<KP1, 3><<<dim3(32, 16, 1), dim3(256), 0, stream>>>(
        flat, wt + OFF_PW1, pb1, ph, nullptr, nullptr, nullptr,
        nullptr, nullptr, nullptr, EE, nullptr, nullptr, nullptr);
    // MLP2: ph @ w2 + b2 + temb + pe -> x (fp32)
    gemm_mfma<EE, 4><<<dim3(32, 16, 1), dim3(256), 0, stream>>>(
        ph, wt + OFF_PW2, pb2, x, nullptr, nullptr, nullptr,
        nullptr, nullptr, nullptr, EE, tokens, temb, pe);

    for (int i = 0; i < NLAYER; ++i) {
        // LN1 -> aob reused? no: xn shares vswz? keep dedicated: use ph as xn
        // (ph is dead after MLP2 of the prologue; safe for both layers)
        unsigned short* xn = ph;
        ln_bf16<<<dim3(512), dim3(256), 0, stream>>>(x, ln1g + i * EE, ln1b + i * EE, xn);
        // QKV (one launch, z = 3) -> bf16 attention layouts
        gemm_mfma<EE, 0><<<dim3(32, 16, 3), dim3(256), 0, stream>>>(
            xn,
            wt + OFF_QKVO + (size_t)(i * 4 + 0) * 65536, bq + i * EE, qb16,
            wt + OFF_QKVO + (size_t)(i * 4 + 1) * 65536, bk + i * EE, kswz,
            wt + OFF_QKVO + (size_t)(i * 4 + 2) * 65536, bv + i * EE, vswz,
            EE, nullptr, nullptr, nullptr);
        // flash attention partials (m-split x4) + merge -> aob bf16
        attn_part_mfma<<<dim3(64, HH, BB), dim3(256), 0, stream>>>(
            qb16, kswz, vswz, bias, mask, gate + i * HH, Opart, statsM, statsL);
        attn_merge<<<dim3(2048), dim3(256), 0, stream>>>(Opart, statsM, statsL, mask, aob);
        // O-proj + residual: x += aob @ wo + bo
        gemm_mfma<EE, 1><<<dim3(32, 16, 1), dim3(256), 0, stream>>>(
            aob, wt + OFF_QKVO + (size_t)(i * 4 + 3) * 65536, bo + i * EE, x,
            nullptr, nullptr, nullptr, nullptr, nullptr, nullptr,
            EE, nullptr, nullptr, nullptr);
        // LN2 -> xn
        ln_bf16<<<dim3(512), dim3(256), 0, stream>>>(x, ln2g + i * EE, ln2b + i * EE, xn);
        // FFN1: gelu(xn @ fw1 + fb1) -> ffh (bf16)
        gemm_mfma<EE, 2><<<dim3(32, 32, 1), dim3(256), 0, stream>>>(
            xn, wt + OFF_FW1 + (size_t)i * 131072, fb1 + i * HIDN, ffh,
            nullptr, nullptr, nullptr, nullptr, nullptr, nullptr,
            HIDN, nullptr, nullptr, nullptr);
        // FFN2: x += ffh @ fw2 + fb2
        gemm_mfma<HIDN, 1><<<dim3(32, 16, 1), dim3(256), 0, stream>>>(
            ffh, wt + OFF_FW2 + (size_t)i * 131072, fb2 + i * EE, x,
            nullptr, nullptr, nullptr, nullptr, nullptr, nullptr,
            EE, nullptr, nullptr, nullptr);
    }

    pool_head<<<dim3(BB), dim3(1024), 0, stream>>>(
        x, mask, hlng, hlnb, hw1, hb1, hw2, hb2, (float*)d_out);

    (void)in_sizes; (void)n_in; (void)out_size; (void)ws_size;
}